// Round 3
// baseline (1727.812 us; speedup 1.0000x reference)
//
#include <hip/hip_runtime.h>

// ---------------------------------------------------------------------------
// Bidirectional 2-layer GRU (B=256, L=200, IN=512, H=256) + FC heads.
// R3: gru restructured: 8 waves/block, amdgpu_waves_per_eu(2,2) so all three
//     gates' h-weights stay VGPR-resident (192 regs). xi staged via async
//     global_load_lds double buffer; h out-stores coalesced via LDS.
// ---------------------------------------------------------------------------

typedef _Float16 half8 __attribute__((ext_vector_type(8)));
typedef _Float16 half4v __attribute__((ext_vector_type(4)));
typedef float fx4 __attribute__((ext_vector_type(4)));

#define BATCH 256
#define SEQ   200
#define HID   256
#define MROWS (BATCH*SEQ)   // 51200
#define NG    1536          // 3H * 2 directions
#define KDIM  512

__device__ __forceinline__ void gload_lds16(const _Float16* g, _Float16* l) {
  __builtin_amdgcn_global_load_lds((const __attribute__((address_space(1))) void*)g,
                                   (__attribute__((address_space(3))) void*)l, 16, 0, 0);
}

// ---------------------------- prep kernels ---------------------------------

__global__ __launch_bounds__(256) void k_cast_x(const float4* __restrict__ x,
                                                half4v* __restrict__ xh, int n4) {
  int i = blockIdx.x * 256 + threadIdx.x;
  if (i < n4) {
    float4 v = x[i];
    half4v o;
    o[0] = (_Float16)v.x; o[1] = (_Float16)v.y; o[2] = (_Float16)v.z; o[3] = (_Float16)v.w;
    xh[i] = o;
  }
}

__global__ __launch_bounds__(256) void k_prep_wih(const float* __restrict__ wf,
                                                  const float* __restrict__ wr,
                                                  const float* __restrict__ bf_,
                                                  const float* __restrict__ br_,
                                                  _Float16* __restrict__ wcat,
                                                  float* __restrict__ bcat) {
  int idx = blockIdx.x * 256 + threadIdx.x;     // < 1536*512
  int n = idx >> 9;
  float v = (n < 768) ? wf[idx] : wr[idx - 768 * 512];
  wcat[idx] = (_Float16)v;
  if (idx < 1536) bcat[idx] = (idx < 768) ? bf_[idx] : br_[idx - 768];
}

// Pack w_hh into MFMA B-fragment order: [dir][T(16)][gate(3)][kf(8)][lane(64)][i(8)]
__global__ __launch_bounds__(256) void k_prep_whh(const float* __restrict__ whf,
                                                  const float* __restrict__ whr,
                                                  _Float16* __restrict__ whp) {
  int e = blockIdx.x * 256 + threadIdx.x;       // < 2*196608
  int dir = e / 196608;
  int r = e - dir * 196608;
  int w = r / 12288;  int r2 = r - w * 12288;
  int gate = r2 >> 12; int r3 = r2 & 4095;
  int kf = r3 >> 9;    int r4 = r3 & 511;
  int lane = r4 >> 3;  int i = r4 & 7;
  int row = gate * 256 + w * 16 + (lane & 15);
  int col = kf * 32 + (lane >> 4) * 8 + i;
  const float* src = dir ? whr : whf;
  whp[e] = (_Float16)src[row * 256 + col];
}

// ---------------------------- xi GEMM (m97 structure) ----------------------
__global__ __launch_bounds__(256) void k_gemm(const _Float16* __restrict__ A,
                                              const _Float16* __restrict__ Wt,
                                              const float* __restrict__ bias,
                                              _Float16* __restrict__ C) {
  __shared__ __align__(16) _Float16 As[128 * 32];
  __shared__ __align__(16) _Float16 Bs[128 * 32];
  const int tid = threadIdx.x;
  const int wv = tid >> 6, ln = tid & 63;
  const int wm = wv >> 1, wn = wv & 1;
  const int jl = ln & 15, q = ln >> 4;
  const int m0 = blockIdx.x * 128, n0 = blockIdx.y * 128;

  const int r0 = tid >> 2, k80 = (tid & 3) * 8;
  const int r1 = r0 + 64;

  fx4 acc[4][4];
#pragma unroll
  for (int a = 0; a < 4; ++a)
#pragma unroll
    for (int b = 0; b < 4; ++b) acc[a][b] = (fx4){0.f, 0.f, 0.f, 0.f};

  for (int kk = 0; kk < KDIM; kk += 32) {
    gload_lds16(A  + (size_t)(m0 + r0) * KDIM + kk + k80, As + tid * 8);
    gload_lds16(A  + (size_t)(m0 + r1) * KDIM + kk + k80, As + (tid + 256) * 8);
    gload_lds16(Wt + (size_t)(n0 + r0) * KDIM + kk + k80, Bs + tid * 8);
    gload_lds16(Wt + (size_t)(n0 + r1) * KDIM + kk + k80, Bs + (tid + 256) * 8);
    __syncthreads();
    half8 af[4], bfr[4];
#pragma unroll
    for (int mt = 0; mt < 4; ++mt)
      af[mt] = *(const half8*)(As + (wm * 64 + mt * 16 + jl) * 32 + q * 8);
#pragma unroll
    for (int nt = 0; nt < 4; ++nt)
      bfr[nt] = *(const half8*)(Bs + (wn * 64 + nt * 16 + jl) * 32 + q * 8);
#pragma unroll
    for (int mt = 0; mt < 4; ++mt)
#pragma unroll
      for (int nt = 0; nt < 4; ++nt)
        acc[mt][nt] = __builtin_amdgcn_mfma_f32_16x16x32_f16(af[mt], bfr[nt], acc[mt][nt], 0, 0, 0);
    __syncthreads();
  }

  float bsv[4];
#pragma unroll
  for (int nt = 0; nt < 4; ++nt) bsv[nt] = bias[n0 + wn * 64 + nt * 16 + jl];

  for (int mt = 0; mt < 4; ++mt) {
#pragma unroll
    for (int nt = 0; nt < 4; ++nt)
#pragma unroll
      for (int rg = 0; rg < 4; ++rg)
        As[(wm * 16 + q * 4 + rg) * 128 + wn * 64 + nt * 16 + jl] =
            (_Float16)(acc[mt][nt][rg] + bsv[nt]);
    __syncthreads();
#pragma unroll
    for (int i = 0; i < 2; ++i) {
      int idx = i * 256 + tid;
      int rl = idx >> 4, c8 = idx & 15;
      int grow = m0 + (rl >> 4) * 64 + mt * 16 + (rl & 15);
      *(half8*)(C + (size_t)grow * NG + n0 + c8 * 8) = *(const half8*)(As + rl * 128 + c8 * 8);
    }
    __syncthreads();
  }
}

// ---------------------------- GRU recurrence -------------------------------
// 32 blocks (16 batch-tiles x 2 dirs), 8 waves of 64. Wave w owns hidden
// [32w, 32w+32) as two 16-wide j-tiles; all 3 gates' weights VGPR-resident
// (amdgpu_waves_per_eu(2,2) -> 256-reg budget, no remat). xi double-buffered
// in LDS via async global_load_lds; h double-buffered in LDS (pad 264).
__global__ __launch_bounds__(512) __attribute__((amdgpu_waves_per_eu(2, 2)))
void k_gru(const _Float16* __restrict__ xi,
           const _Float16* __restrict__ whp,
           const float* __restrict__ bhhf,
           const float* __restrict__ bhhr,
           _Float16* __restrict__ out) {
  extern __shared__ _Float16 smem[];
  _Float16* xib0 = smem;              // 16*768 = 12288
  _Float16* xib1 = smem + 12288;
  _Float16* hbf0 = smem + 24576;      // 16*264 = 4224
  _Float16* hbf1 = smem + 28800;      // total 33024 halves = 66048 B

  const int tid = threadIdx.x, w = tid >> 6, ln = tid & 63;
  const int jl = ln & 15, q = ln >> 4;
  const int bt = blockIdx.x, dir = blockIdx.y;
  const float* bhh = dir ? bhhr : bhhf;

  // ---- xi DMA setup: 1536 chunks of 8 halves (16B); 3 per thread ----
  const long long t0 = dir ? (SEQ - 1) : 0;
  const int xstep = dir ? -NG : NG;
  const _Float16* pk[3];
  int coff[3];
#pragma unroll
  for (int k = 0; k < 3; ++k) {
    int c = k * 512 + tid;
    int rk = c / 96, ck = c - rk * 96;
    coff[k] = c * 8;
    pk[k] = xi + ((size_t)((bt * 16 + rk) * SEQ) + t0) * NG + dir * 768 + ck * 8;
    gload_lds16(pk[k], xib0 + coff[k]);   // preload t0
  }

  // ---- resident weights: [tile][gate][kf] = 48 half8 = 192 VGPRs ----
  half8 wf[2][3][8];
#pragma unroll
  for (int tt = 0; tt < 2; ++tt)
#pragma unroll
    for (int g = 0; g < 3; ++g)
#pragma unroll
      for (int kf = 0; kf < 8; ++kf)
        wf[tt][g][kf] = *(const half8*)(whp + ((size_t)(dir * 16 + w * 2 + tt)) * 12288
                                        + g * 4096 + kf * 512 + ln * 8);
  float bh[2][3];
#pragma unroll
  for (int tt = 0; tt < 2; ++tt)
#pragma unroll
    for (int g = 0; g < 3; ++g)
      bh[tt][g] = bhh[g * 256 + w * 32 + tt * 16 + jl];

  for (int i = tid; i < 4224; i += 512) hbf0[i] = (_Float16)0.f;

  // ---- coalesced out-store setup (1 step delayed) ----
  const int orow = tid >> 5, ochk = tid & 31;
  _Float16* opp = out + ((size_t)((bt * 16 + orow) * SEQ) + t0) * 512 + dir * 256 + ochk * 8;
  const int ostep = dir ? -512 : 512;
  const int osbase = orow * 264 + ochk * 8;

  // per-lane LDS element bases
  const int xbase  = (q * 4) * 768 + w * 32 + jl;  // + rg*768 + g*256 + tt*16
  const int habase = jl * 264 + q * 8;             // + kf*32
  const int hwbase = (q * 4) * 264 + w * 32 + jl;  // + rg*264 + tt*16

  float hprev[2][4] = {{0.f,0.f,0.f,0.f},{0.f,0.f,0.f,0.f}};
  __syncthreads();   // drains t0 DMA (vmcnt) + h zero init

  for (int s = 0; s < SEQ; ++s) {
    const _Float16* xr = (s & 1) ? xib1 : xib0;
    _Float16*       xw = (s & 1) ? xib0 : xib1;
    const _Float16* hr = (s & 1) ? hbf1 : hbf0;
    _Float16*       hw = (s & 1) ? hbf0 : hbf1;

    // async prefetch xi(t(s+1))
    if (s < SEQ - 1) {
#pragma unroll
      for (int k = 0; k < 3; ++k) {
        pk[k] += xstep;
        gload_lds16(pk[k], xw + coff[k]);
      }
    }
    // coalesced store of h(s-1) (resides in hr's buffer)
    if (s > 0) {
      *(half8*)opp = *(const half8*)(hr + osbase);
      opp += ostep;
    }

    fx4 acc[2][3];
#pragma unroll
    for (int tt = 0; tt < 2; ++tt)
#pragma unroll
      for (int g = 0; g < 3; ++g) acc[tt][g] = (fx4){0.f, 0.f, 0.f, 0.f};

#pragma unroll
    for (int kf = 0; kf < 8; ++kf) {
      half8 a = *(const half8*)(hr + habase + kf * 32);
#pragma unroll
      for (int tt = 0; tt < 2; ++tt)
#pragma unroll
        for (int g = 0; g < 3; ++g)
          acc[tt][g] = __builtin_amdgcn_mfma_f32_16x16x32_f16(a, wf[tt][g][kf], acc[tt][g], 0, 0, 0);
    }

#pragma unroll
    for (int tt = 0; tt < 2; ++tt)
#pragma unroll
      for (int rg = 0; rg < 4; ++rg) {
        float ir  = (float)xr[xbase + rg * 768 + tt * 16];
        float iz  = (float)xr[xbase + rg * 768 + 256 + tt * 16];
        float inn = (float)xr[xbase + rg * 768 + 512 + tt * 16];
        float r = __builtin_amdgcn_rcpf(1.f + __expf(-(acc[tt][0][rg] + bh[tt][0] + ir)));
        float z = __builtin_amdgcn_rcpf(1.f + __expf(-(acc[tt][1][rg] + bh[tt][1] + iz)));
        float gn = inn + r * (acc[tt][2][rg] + bh[tt][2]);
        gn = fminf(fmaxf(gn, -9.f), 9.f);
        float e2 = __expf(2.f * gn);
        float nn = (e2 - 1.f) * __builtin_amdgcn_rcpf(e2 + 1.f);
        float h = (1.f - z) * nn + z * hprev[tt][rg];
        hprev[tt][rg] = h;
        hw[hwbase + rg * 264 + tt * 16] = (_Float16)h;
      }
    __syncthreads();   // h(s) + xi(s+1) ready for next step
  }
  // flush h(SEQ-1): it lives in hbf[SEQ&1] = hbf0
  *(half8*)opp = *(const half8*)(hbf0 + osbase);
}

// ---------------------------- heads ----------------------------------------

__global__ __launch_bounds__(256) void k_heads1(const _Float16* __restrict__ out,
                                                const float* __restrict__ fc1w,
                                                const float* __restrict__ fc1b,
                                                const float* __restrict__ fc2w,
                                                const float* __restrict__ fc2b,
                                                float* __restrict__ y,
                                                float* __restrict__ y2) {
  int gw = (blockIdx.x * 256 + threadIdx.x) >> 6;
  int ln = threadIdx.x & 63;
  int b = gw / SEQ, t = gw - b * SEQ;
  half8 ov = *(const half8*)(out + (size_t)gw * 512 + ln * 8);
  float o[8];
#pragma unroll
  for (int i = 0; i < 8; ++i) o[i] = (float)ov[i];

  float4 w1a = *(const float4*)(fc1w + ln * 8);
  float4 w1b = *(const float4*)(fc1w + ln * 8 + 4);
  float s1 = o[0]*w1a.x + o[1]*w1a.y + o[2]*w1a.z + o[3]*w1a.w
           + o[4]*w1b.x + o[5]*w1b.y + o[6]*w1b.z + o[7]*w1b.w;
  float s2[10];
#pragma unroll
  for (int c = 0; c < 10; ++c) {
    float4 wa = *(const float4*)(fc2w + c * 512 + ln * 8);
    float4 wbv = *(const float4*)(fc2w + c * 512 + ln * 8 + 4);
    s2[c] = o[0]*wa.x + o[1]*wa.y + o[2]*wa.z + o[3]*wa.w
          + o[4]*wbv.x + o[5]*wbv.y + o[6]*wbv.z + o[7]*wbv.w;
  }
#pragma unroll
  for (int m = 32; m; m >>= 1) {
    s1 += __shfl_xor(s1, m);
#pragma unroll
    for (int c = 0; c < 10; ++c) s2[c] += __shfl_xor(s2[c], m);
  }
  if (ln == 0) {
    y[gw] = s1 + fc1b[0];
    float* y2p = y2 + (size_t)b * 2000 + t * 10;
#pragma unroll
    for (int c = 0; c < 10; ++c) y2p[c] = s2[c] + fc2b[c];
  }
}

__device__ __forceinline__ float blkRedMax(float v, float* red, int tid) {
#pragma unroll
  for (int m = 32; m; m >>= 1) v = fmaxf(v, __shfl_xor(v, m));
  __syncthreads();
  if ((tid & 63) == 0) red[tid >> 6] = v;
  __syncthreads();
  return fmaxf(fmaxf(red[0], red[1]), fmaxf(red[2], red[3]));
}
__device__ __forceinline__ float blkRedSum(float v, float* red, int tid) {
#pragma unroll
  for (int m = 32; m; m >>= 1) v += __shfl_xor(v, m);
  __syncthreads();
  if ((tid & 63) == 0) red[tid >> 6] = v;
  __syncthreads();
  return red[0] + red[1] + red[2] + red[3];
}

__global__ __launch_bounds__(256) void k_heads2(const float* __restrict__ y,
                                                const float* __restrict__ y2,
                                                float* __restrict__ y3) {
  __shared__ float sp[SEQ];
  __shared__ float se[2000];
  __shared__ float red[4];
  int b = blockIdx.x, tid = threadIdx.x;

  float v = (tid < SEQ) ? y[(size_t)b * SEQ + tid] : -3.0e38f;
  float mx = blkRedMax(v, red, tid);
  float e = (tid < SEQ) ? __expf(v - mx) : 0.f;
  float sum = blkRedSum(e, red, tid);
  if (tid < SEQ) sp[tid] = e / (sum * 10.f);

  float vv[8];
  float lm = -3.0e38f;
#pragma unroll
  for (int r = 0; r < 8; ++r) {
    int k = tid + r * 256;
    vv[r] = (k < 2000) ? y2[(size_t)b * 2000 + k] : -3.0e38f;
    lm = fmaxf(lm, vv[r]);
  }
  float mx2 = blkRedMax(lm, red, tid);
  float ls = 0.f;
#pragma unroll
  for (int r = 0; r < 8; ++r) {
    int k = tid + r * 256;
    if (k < 2000) { float ee = __expf(vv[r] - mx2); se[k] = ee; ls += ee; }
  }
  float sum2 = blkRedSum(ls, red, tid);
  __syncthreads();
  float inv = 1.f / sum2;
#pragma unroll
  for (int r = 0; r < 8; ++r) {
    int k = tid + r * 256;
    if (k < 2000) y3[(size_t)b * 2000 + k] = se[k] * inv + sp[k / 10];
  }
}

// ---------------------------- launch ---------------------------------------

extern "C" void kernel_launch(void* const* d_in, const int* in_sizes, int n_in,
                              void* d_out, int out_size, void* d_ws, size_t ws_size,
                              hipStream_t stream) {
  const float* x     = (const float*)d_in[0];
  const float* wih0  = (const float*)d_in[1];
  const float* whh0  = (const float*)d_in[2];
  const float* bih0  = (const float*)d_in[3];
  const float* bhh0  = (const float*)d_in[4];
  const float* wih0r = (const float*)d_in[5];
  const float* whh0r = (const float*)d_in[6];
  const float* bih0r = (const float*)d_in[7];
  const float* bhh0r = (const float*)d_in[8];
  const float* wih1  = (const float*)d_in[9];
  const float* whh1  = (const float*)d_in[10];
  const float* bih1  = (const float*)d_in[11];
  const float* bhh1  = (const float*)d_in[12];
  const float* wih1r = (const float*)d_in[13];
  const float* whh1r = (const float*)d_in[14];
  const float* bih1r = (const float*)d_in[15];
  const float* bhh1r = (const float*)d_in[16];
  const float* fc1w  = (const float*)d_in[17];
  const float* fc1b  = (const float*)d_in[18];
  const float* fc2w  = (const float*)d_in[19];
  const float* fc2b  = (const float*)d_in[20];

  char* ws = (char*)d_ws;
  _Float16* xh    = (_Float16*)(ws + 0);
  _Float16* xi    = (_Float16*)(ws + 52428800);
  _Float16* l0    = (_Float16*)(ws + 209715200);
  _Float16* outh  = (_Float16*)(ws + 262144000);
  _Float16* wcat0 = (_Float16*)(ws + 314572800);
  _Float16* wcat1 = (_Float16*)(ws + 316145664);
  _Float16* whp0  = (_Float16*)(ws + 317718528);
  _Float16* whp1  = (_Float16*)(ws + 318504960);
  float*    bcat0 = (float*)(ws + 319291392);
  float*    bcat1 = (float*)(ws + 319297536);

  float* y  = (float*)d_out;
  float* y2 = (float*)d_out + 51200;
  float* y3 = (float*)d_out + 563200;

  k_cast_x<<<25600, 256, 0, stream>>>((const float4*)x, (half4v*)xh, 6553600);
  k_prep_wih<<<3072, 256, 0, stream>>>(wih0, wih0r, bih0, bih0r, wcat0, bcat0);
  k_prep_wih<<<3072, 256, 0, stream>>>(wih1, wih1r, bih1, bih1r, wcat1, bcat1);
  k_prep_whh<<<1536, 256, 0, stream>>>(whh0, whh0r, whp0);
  k_prep_whh<<<1536, 256, 0, stream>>>(whh1, whh1r, whp1);

  hipFuncSetAttribute(reinterpret_cast<const void*>(k_gru),
                      hipFuncAttributeMaxDynamicSharedMemorySize, 66048);

  k_gemm<<<dim3(400, 12), 256, 0, stream>>>(xh, wcat0, bcat0, xi);
  k_gru<<<dim3(16, 2), 512, 66048, stream>>>(xi, whp0, bhh0, bhh0r, l0);
  k_gemm<<<dim3(400, 12), 256, 0, stream>>>(l0, wcat1, bcat1, xi);
  k_gru<<<dim3(16, 2), 512, 66048, stream>>>(xi, whp1, bhh1, bhh1r, outh);
  k_heads1<<<12800, 256, 0, stream>>>(outh, fc1w, fc1b, fc2w, fc2b, y, y2);
  k_heads2<<<256, 256, 0, stream>>>(y, y2, y3);
}